// Round 5
// baseline (147.161 us; speedup 1.0000x reference)
//
#include <hip/hip_runtime.h>
#include <stdint.h>

// ---------------------------------------------------------------------------
// PoseFeatureExtractor fused kernel for MI355X (gfx950) — round 9
//   r4 skeleton (direct global phase-0 reads, NO staging, plain stores,
//   MT=64) + temporal fold (vel/acc/jw folded into W1'', K=352, fp16 —
//   r5/r7 proven, absmax 0.0078) + split slim LDS (ccb/ab; 33,792 B) ->
//   4 blocks/CU, 32 waves via __launch_bounds__(512,8).
//   - 0c is now center-only: 66x25 items x ~18 VALU (was 64x25 x ~70)
//   - plain scalar epilogue stores (r4-proven WRITE_SIZE == 64MiB exact)
//   - biases in MFMA C-in; 0ab merged shfl reduce (r8-proven)
// ---------------------------------------------------------------------------

#define S_    2048
#define MT_   64
#define TPB   512
#define HID_  256
#define OUT_  128

typedef __attribute__((ext_vector_type(8))) _Float16 half8;   // fp16x8 MFMA frag
typedef __attribute__((ext_vector_type(4))) float    floatx4; // fp32x4 MFMA acc

// edge tables packed as nibbles: c0[e] = (C0M>>4e)&15 ; c1[e] = ((C1M>>4e)&15)+1
#define C0M 0x0ECDB118675110ULL
#define C1M 0x0FDECBA9786540ULL

// |err| <= 6.7e-5 abs (A&S 4.4.45) — far below fp16 feature quantization
__device__ __forceinline__ float facos(float x) {
    float ax = fabsf(x);
    float p = fmaf(ax, -0.0187293f, 0.0742610f);
    p = fmaf(ax, p, -0.2121144f);
    p = fmaf(ax, p, 1.5707288f);
    float r = __builtin_amdgcn_sqrtf(1.f - ax) * p;
    return x < 0.f ? 3.14159265358979f - r : r;
}

// --------------------------- prep kernel -----------------------------------
// Build W1'' (BN-fold + temporal-fold + jw-fold), fp16, MFMA-B-fragment order.
// K layout: [cc(s) 0..95][cc(s-1) 96..191][cc(s-2) 192..287][ang 288..351]
//   d0 rows: (Wp+Wv+Wa)*a*jw ; d1: -(Wv+2Wa)*a*jw ; d2: Wa*a*jw ; ang: Wang*a*jw
// Rows loc>=75 (cc) / q>=39 (ang) are ZERO — the main kernel's A-reads that
// cross a frame/row boundary land on these rows (exactness requirement).
__global__ void prep_kernel(const float* __restrict__ W1, const float* __restrict__ b1,
                            const float* __restrict__ gamma, const float* __restrict__ beta,
                            const float* __restrict__ rmean, const float* __restrict__ rvar,
                            const float* __restrict__ W2, const float* __restrict__ jw,
                            _Float16* __restrict__ w1p,
                            _Float16* __restrict__ w2p,
                            float* __restrict__ b1p) {
    int bid = blockIdx.x, tid = threadIdx.x;
    if (bid < 352) {                         // W1'' row k = bid, n = tid
        int k = bid, n = tid;
        float a = gamma[n] * __builtin_amdgcn_rsqf(rvar[n] + 1e-5f);
        float v = 0.f;
        if (k < 288) {
            int d = k / 96, loc = k - d * 96;        // scalar (uniform) math
            if (loc < 75) {
                int j = loc / 3, c = loc - j * 3;
                const float* Wb = W1 + (j * 12 + c) * HID_ + n;
                float wp = Wb[0], wv = Wb[3 * HID_], wa = Wb[6 * HID_];
                float t = (d == 0) ? (wp + wv + wa) : (d == 1 ? -(wv + 2.f * wa) : wa);
                v = t * a * jw[j];
            }
        } else {
            int q = k - 288;
            if (q < 39) {
                int e = q / 3, aa = q - e * 3;
                v = W1[(e * 12 + 9 + aa) * HID_ + n] * a * jw[e];
            }
        }
        int blk = (k >> 5) * 16 + (n >> 4);
        int off = blk * 512 + (((k >> 3) & 3) * 16 + (n & 15)) * 8 + (k & 7);
        w1p[off] = (_Float16)v;
    } else if (bid < 480) {                  // W2 packed fp16, 2 rows/block
        int i2 = (bid - 352) * 256 + tid;
        int k = i2 >> 7, n = i2 & 127;
        int blk = (k >> 5) * 8 + (n >> 4);
        int off = blk * 512 + (((k >> 3) & 3) * 16 + (n & 15)) * 8 + (k & 7);
        w2p[off] = (_Float16)W2[k * OUT_ + n];
    } else {                                 // folded bias
        int n = tid;
        float a = gamma[n] * __builtin_amdgcn_rsqf(rvar[n] + 1e-5f);
        b1p[n] = fmaf(a, b1[n] - rmean[n], beta[n]);
    }
}

// --------------------------- main fused kernel ------------------------------
// LDS: ccb 66 x 88 halfs (+8 slack)  11632 B (176B rows: 8 banks 2-way, free)
//      ab  64 x 40 halfs (+24 slack)  5168 B ( 80B rows: 8 banks 2-way, free)
//      rs  66 float4 (root, scale)    1056 B (dead after 0c)
//      hid 64 x 264 halfs overlays [0..33792) after GEMM1 barrier.
#define L_CCB 0
#define L_AB  11632
#define L_RS  16800
#define L_TOT 33792                  // granule 33792 -> 4 blocks/CU, 32 waves

__global__ __launch_bounds__(TPB, 8) void pose_mlp(
    const float* __restrict__ poses,
    const _Float16* __restrict__ w1p,
    const _Float16* __restrict__ w2p,
    const float* __restrict__ b1p,
    const float* __restrict__ b2,
    float* __restrict__ out)
{
    __shared__ __align__(16) unsigned char smem[L_TOT];
    const int tid  = threadIdx.x;
    const int lane = tid & 63;
    const int wv   = tid >> 6;               // 0..7
    const int t0   = blockIdx.x * MT_;
    const int s0   = t0 & (S_ - 1);

    _Float16* ccb = (_Float16*)(smem + L_CCB);
    _Float16* ab  = (_Float16*)(smem + L_AB);
    float4*   rs  = (float4*)(smem + L_RS);

    // early prefetch: GEMM1 kc=0 B-frags + biases (independent of LDS)
    half8 bw[2];
    #pragma unroll
    for (int ni = 0; ni < 2; ni++)
        bw[ni] = *(const half8*)(w1p + (unsigned)(wv * 2 + ni) * 512 + lane * 8);
    float bv[2];
    #pragma unroll
    for (int ni = 0; ni < 2; ni++) bv[ni] = b1p[wv * 32 + ni * 16 + (lane & 15)];
    float c2 = b2[wv * 16 + (lane & 15)];

    // zero constant-pad slots: ccb slack row (8), ab slack (24), ab col39 (64)
    if (tid < 96) {
        if (tid < 8)       ccb[66 * 88 + tid] = (_Float16)0.f;
        else if (tid < 32) ab[64 * 40 + (tid - 8)] = (_Float16)0.f;
        else               ab[(tid - 32) * 40 + 39] = (_Float16)0.f;
    }

    // ---- 0d: joint angles -> ab (direct global; v/||v|| centering-invariant)
    #pragma unroll
    for (int r2 = 0; r2 < 2; r2++) {
        int i = r2 * TPB + tid;              // 0..1023
        int tt = i >> 4, e = i & 15;
        if (e < 13) {
            const float* P = poses + (size_t)(t0 + tt) * 75;
            int a0 = (int)((C0M >> (4 * e)) & 15) * 3;
            int a1 = (((int)((C1M >> (4 * e)) & 15)) + 1) * 3;
            float vx = P[a1] - P[a0], vy = P[a1+1] - P[a0+1], vz = P[a1+2] - P[a0+2];
            float d  = fmaf(vx, vx, fmaf(vy, vy, vz * vz));
            float inv = __builtin_amdgcn_rcpf(fmaxf(__builtin_amdgcn_sqrtf(d), 1e-12f));
            _Float16* A = ab + tt * 40;
            A[e * 3 + 0] = (_Float16)facos(fminf(fmaxf(vx * inv, -1.f), 1.f));
            A[e * 3 + 1] = (_Float16)facos(fminf(fmaxf(vy * inv, -1.f), 1.f));
            A[e * 3 + 2] = (_Float16)facos(fminf(fmaxf(vz * inv, -1.f), 1.f));
        }
    }

    // ---- 0ab: root + scale per frame (66 frames x 4 lanes, shfl reduce) ----
    // per-batch clamp: frames f=0,1 map to frame t0 when s0==0 (this makes
    // the temporal fold reproduce the reference's zero-padded vel/acc).
    if (tid < 264) {
        int f = tid >> 2, q = tid & 3;
        int g = t0 + f - 2;
        if (s0 == 0 && f < 2) g = t0;
        const float* P = poses + (size_t)g * 75;
        float r0 = P[0], r1 = P[1], r2 = P[2];
        float m2 = 0.f;
        #pragma unroll
        for (int jj = 0; jj < 7; jj++) {
            int j = q * 7 + jj;
            if (j < 25) {
                float dx = P[j*3]   - r0;
                float dy = P[j*3+1] - r1;
                float dz = P[j*3+2] - r2;
                m2 = fmaxf(m2, fmaf(dx, dx, fmaf(dy, dy, dz * dz)));
            }
        }
        m2 = fmaxf(m2, __shfl_xor(m2, 1));
        m2 = fmaxf(m2, __shfl_xor(m2, 2));
        if (q == 0) {
            float sc = __builtin_amdgcn_rcpf(__builtin_amdgcn_sqrtf(m2) + 1e-8f);
            rs[f] = make_float4(r0, r1, r2, sc);
        }
    }
    __syncthreads();

    // ---- 0c: center+scale -> ccb fp16 (j>=25 lanes zero cols 75..87) ----
    #pragma unroll 1
    for (int i = tid; i < 66 * 32; i += TPB) {
        int f = i >> 5, j = i & 31;
        _Float16* C = ccb + f * 88;
        if (j < 25) {
            int g = t0 + f - 2;
            if (s0 == 0 && f < 2) g = t0;
            const float* P = poses + (size_t)g * 75 + j * 3;
            float4 q = rs[f];
            C[j * 3 + 0] = (_Float16)((P[0] - q.x) * q.w);
            C[j * 3 + 1] = (_Float16)((P[1] - q.y) * q.w);
            C[j * 3 + 2] = (_Float16)((P[2] - q.z) * q.w);
        } else {
            int c = 75 + (j - 25) * 2;
            C[c] = (_Float16)0.f;
            if (c + 1 < 88) C[c + 1] = (_Float16)0.f;
        }
    }
    __syncthreads();

    // ---- GEMM1: hid = relu(A @ W1'' + b1'); K=352; bias in MFMA C-in ----
    floatx4 acc[4][2];
    #pragma unroll
    for (int mi = 0; mi < 4; mi++)
        #pragma unroll
        for (int ni = 0; ni < 2; ni++)
            acc[mi][ni] = (floatx4){bv[ni], bv[ni], bv[ni], bv[ni]};

    int rowb[4];
    #pragma unroll
    for (int mi = 0; mi < 4; mi++)           // (token+2)*88 + (l>>4)*8
        rowb[mi] = (mi * 16 + (lane & 15) + 2) * 88 + (lane >> 4) * 8;

    int koff = 0;                            // region walk (see r7)
    #pragma unroll 1
    for (int kc = 0; kc < 9; kc++) {         // cc regions d = kc/3
        half8 bn[2];
        #pragma unroll
        for (int ni = 0; ni < 2; ni++)
            bn[ni] = *(const half8*)(w1p + (unsigned)((kc + 1) * 16 + wv * 2 + ni) * 512 + lane * 8);
        half8 af[4];
        #pragma unroll
        for (int mi = 0; mi < 4; mi++)
            af[mi] = *(const half8*)(ccb + rowb[mi] + koff);
        #pragma unroll
        for (int mi = 0; mi < 4; mi++)
            #pragma unroll
            for (int ni = 0; ni < 2; ni++)
                acc[mi][ni] = __builtin_amdgcn_mfma_f32_16x16x32_f16(
                    af[mi], bw[ni], acc[mi][ni], 0, 0, 0);
        bw[0] = bn[0]; bw[1] = bn[1];
        koff += 32; if (kc == 2 || kc == 5) koff -= 184;   // next region
    }
    {   // kc = 9,10: angle region from ab
        int rowa[4];
        #pragma unroll
        for (int mi = 0; mi < 4; mi++)
            rowa[mi] = (mi * 16 + (lane & 15)) * 40 + (lane >> 4) * 8;
        #pragma unroll
        for (int kc = 9; kc < 11; kc++) {
            half8 bn[2];
            if (kc < 10) {
                #pragma unroll
                for (int ni = 0; ni < 2; ni++)
                    bn[ni] = *(const half8*)(w1p + (unsigned)((kc + 1) * 16 + wv * 2 + ni) * 512 + lane * 8);
            }
            half8 af[4];
            #pragma unroll
            for (int mi = 0; mi < 4; mi++)
                af[mi] = *(const half8*)(ab + rowa[mi] + (kc - 9) * 32);
            #pragma unroll
            for (int mi = 0; mi < 4; mi++)
                #pragma unroll
                for (int ni = 0; ni < 2; ni++)
                    acc[mi][ni] = __builtin_amdgcn_mfma_f32_16x16x32_f16(
                        af[mi], bw[ni], acc[mi][ni], 0, 0, 0);
            if (kc < 10) { bw[0] = bn[0]; bw[1] = bn[1]; }
        }
    }

    // preload W2 kc=0 frag (this wave's n-tile), independent of LDS
    half8 bw2 = *(const half8*)(w2p + (unsigned)wv * 512 + lane * 8);

    __syncthreads();   // all waves done reading ccb/ab/rs

    _Float16* hid = (_Float16*)smem;         // 64 x 264, overlays ccb/ab/rs
    #pragma unroll
    for (int mi = 0; mi < 4; mi++)
        #pragma unroll
        for (int ni = 0; ni < 2; ni++)
            #pragma unroll
            for (int r = 0; r < 4; r++) {
                float v = fmaxf(acc[mi][ni][r], 0.f);      // bias already in
                int m   = mi * 16 + (lane >> 4) * 4 + r;   // C/D: row=(l>>4)*4+r
                int col = wv * 32 + ni * 16 + (lane & 15); //      col=l&15
                hid[m * 264 + col] = (_Float16)v;
            }
    __syncthreads();   // hid visible

    // ---- GEMM2: out = hid @ W2 + b2; wave wv owns n-tile wv; b2 in C-in ----
    floatx4 acc2[4];
    #pragma unroll
    for (int mi = 0; mi < 4; mi++) acc2[mi] = (floatx4){c2, c2, c2, c2};

    #pragma unroll 1
    for (int kc = 0; kc < 8; kc++) {
        half8 bn2;
        if (kc < 7)
            bn2 = *(const half8*)(w2p + (unsigned)((kc + 1) * 8 + wv) * 512 + lane * 8);
        half8 af[4];
        #pragma unroll
        for (int mi = 0; mi < 4; mi++)
            af[mi] = *(const half8*)(hid + (mi * 16 + (lane & 15)) * 264 + kc * 32 + (lane >> 4) * 8);
        #pragma unroll
        for (int mi = 0; mi < 4; mi++)
            acc2[mi] = __builtin_amdgcn_mfma_f32_16x16x32_f16(
                af[mi], bw2, acc2[mi], 0, 0, 0);
        if (kc < 7) bw2 = bn2;
    }

    // ---- epilogue: PLAIN scalar stores (r4-proven: L2 coalesces to exactly
    //      64MiB HBM writes; NT scalar stores inflate writes — r8 lesson) ----
    #pragma unroll
    for (int mi = 0; mi < 4; mi++)
        #pragma unroll
        for (int r = 0; r < 4; r++) {
            int m   = mi * 16 + (lane >> 4) * 4 + r;
            int col = wv * 16 + (lane & 15);
            out[(size_t)(t0 + m) * OUT_ + col] = acc2[mi][r];
        }
}

// --------------------------- launch -----------------------------------------
extern "C" void kernel_launch(void* const* d_in, const int* in_sizes, int n_in,
                              void* d_out, int out_size, void* d_ws, size_t ws_size,
                              hipStream_t stream) {
    (void)in_sizes; (void)n_in; (void)out_size; (void)ws_size;
    const float* poses = (const float*)d_in[0];
    const float* W1    = (const float*)d_in[1];
    const float* b1    = (const float*)d_in[2];
    const float* gamma = (const float*)d_in[3];
    const float* beta  = (const float*)d_in[4];
    const float* rmean = (const float*)d_in[5];
    const float* rvar  = (const float*)d_in[6];
    const float* W2    = (const float*)d_in[7];
    const float* b2    = (const float*)d_in[8];
    const float* jw    = (const float*)d_in[9];

    _Float16* w1p = (_Float16*)d_ws;                         // 352*256 fp16
    _Float16* w2p = w1p + 352 * HID_;                        // 256*128 fp16
    float* b1p = (float*)((char*)d_ws + (352 * HID_ + HID_ * OUT_) * 2);

    prep_kernel<<<481, 256, 0, stream>>>(W1, b1, gamma, beta, rmean, rvar, W2, jw,
                                         w1p, w2p, b1p);
    pose_mlp<<<2048, TPB, 0, stream>>>(poses, w1p, w2p, b1p, b2, (float*)d_out);
}

// Round 6
// 145.521 us; speedup vs baseline: 1.0113x; 1.0113x over previous
//
#include <hip/hip_runtime.h>
#include <stdint.h>

// ---------------------------------------------------------------------------
// PoseFeatureExtractor fused kernel for MI355X (gfx950) — round 10
//   = round 9 (r4 skeleton + temporal fold, K=352 fp16, split slim LDS,
//     4 blocks/CU) with ONE change: the r6-proven byte-exact epilogue
//     (acc2 -> LDS obuf fp32 -> contiguous per-lane float4 NONTEMPORAL
//     stores; each wave covers 1KB of fully-written lines).
//   r9 lesson: plain scalar stores RMW-inflate writes at 4 blocks/CU
//   (73.7MB vs 65.5MB exact); r6's obuf epilogue measured exactly 65536KB
//   and the lowest FETCH (NT keeps the output stream from evicting
//   L3-resident poses).
// ---------------------------------------------------------------------------

#define S_    2048
#define MT_   64
#define TPB   512
#define HID_  256
#define OUT_  128

typedef __attribute__((ext_vector_type(8))) _Float16 half8;   // fp16x8 MFMA frag
typedef __attribute__((ext_vector_type(4))) float    floatx4; // fp32x4 MFMA acc
typedef __attribute__((ext_vector_type(4))) float    f4_t;    // for NT stores

// edge tables packed as nibbles: c0[e] = (C0M>>4e)&15 ; c1[e] = ((C1M>>4e)&15)+1
#define C0M 0x0ECDB118675110ULL
#define C1M 0x0FDECBA9786540ULL

// |err| <= 6.7e-5 abs (A&S 4.4.45) — far below fp16 feature quantization
__device__ __forceinline__ float facos(float x) {
    float ax = fabsf(x);
    float p = fmaf(ax, -0.0187293f, 0.0742610f);
    p = fmaf(ax, p, -0.2121144f);
    p = fmaf(ax, p, 1.5707288f);
    float r = __builtin_amdgcn_sqrtf(1.f - ax) * p;
    return x < 0.f ? 3.14159265358979f - r : r;
}

// --------------------------- prep kernel -----------------------------------
// Build W1'' (BN-fold + temporal-fold + jw-fold), fp16, MFMA-B-fragment order.
// K layout: [cc(s) 0..95][cc(s-1) 96..191][cc(s-2) 192..287][ang 288..351]
//   d0 rows: (Wp+Wv+Wa)*a*jw ; d1: -(Wv+2Wa)*a*jw ; d2: Wa*a*jw ; ang: Wang*a*jw
// Rows loc>=75 (cc) / q>=39 (ang) are ZERO — the main kernel's A-reads that
// cross a frame/row boundary land on these rows (exactness requirement).
__global__ void prep_kernel(const float* __restrict__ W1, const float* __restrict__ b1,
                            const float* __restrict__ gamma, const float* __restrict__ beta,
                            const float* __restrict__ rmean, const float* __restrict__ rvar,
                            const float* __restrict__ W2, const float* __restrict__ jw,
                            _Float16* __restrict__ w1p,
                            _Float16* __restrict__ w2p,
                            float* __restrict__ b1p) {
    int bid = blockIdx.x, tid = threadIdx.x;
    if (bid < 352) {                         // W1'' row k = bid, n = tid
        int k = bid, n = tid;
        float a = gamma[n] * __builtin_amdgcn_rsqf(rvar[n] + 1e-5f);
        float v = 0.f;
        if (k < 288) {
            int d = k / 96, loc = k - d * 96;        // scalar (uniform) math
            if (loc < 75) {
                int j = loc / 3, c = loc - j * 3;
                const float* Wb = W1 + (j * 12 + c) * HID_ + n;
                float wp = Wb[0], wv = Wb[3 * HID_], wa = Wb[6 * HID_];
                float t = (d == 0) ? (wp + wv + wa) : (d == 1 ? -(wv + 2.f * wa) : wa);
                v = t * a * jw[j];
            }
        } else {
            int q = k - 288;
            if (q < 39) {
                int e = q / 3, aa = q - e * 3;
                v = W1[(e * 12 + 9 + aa) * HID_ + n] * a * jw[e];
            }
        }
        int blk = (k >> 5) * 16 + (n >> 4);
        int off = blk * 512 + (((k >> 3) & 3) * 16 + (n & 15)) * 8 + (k & 7);
        w1p[off] = (_Float16)v;
    } else if (bid < 480) {                  // W2 packed fp16, 2 rows/block
        int i2 = (bid - 352) * 256 + tid;
        int k = i2 >> 7, n = i2 & 127;
        int blk = (k >> 5) * 8 + (n >> 4);
        int off = blk * 512 + (((k >> 3) & 3) * 16 + (n & 15)) * 8 + (k & 7);
        w2p[off] = (_Float16)W2[k * OUT_ + n];
    } else {                                 // folded bias
        int n = tid;
        float a = gamma[n] * __builtin_amdgcn_rsqf(rvar[n] + 1e-5f);
        b1p[n] = fmaf(a, b1[n] - rmean[n], beta[n]);
    }
}

// --------------------------- main fused kernel ------------------------------
// LDS: ccb 66 x 88 halfs (+8 slack)  11632 B (176B rows: 8 banks 2-way, free)
//      ab  64 x 40 halfs (+24 slack)  5168 B ( 80B rows: 8 banks 2-way, free)
//      rs  66 float4 (root, scale)    1056 B (dead after 0c)
//      hid 64 x 264 halfs (33792B) overlays [0..33792) after GEMM1 barrier;
//      obuf 64 x 132 f32 (33792B) overlays the same region after GEMM2.
#define L_CCB 0
#define L_AB  11632
#define L_RS  16800
#define L_TOT 33792                  // granule 33792 -> 4 blocks/CU, 32 waves

__global__ __launch_bounds__(TPB, 8) void pose_mlp(
    const float* __restrict__ poses,
    const _Float16* __restrict__ w1p,
    const _Float16* __restrict__ w2p,
    const float* __restrict__ b1p,
    const float* __restrict__ b2,
    float* __restrict__ out)
{
    __shared__ __align__(16) unsigned char smem[L_TOT];
    const int tid  = threadIdx.x;
    const int lane = tid & 63;
    const int wv   = tid >> 6;               // 0..7
    const int t0   = blockIdx.x * MT_;
    const int s0   = t0 & (S_ - 1);

    _Float16* ccb = (_Float16*)(smem + L_CCB);
    _Float16* ab  = (_Float16*)(smem + L_AB);
    float4*   rs  = (float4*)(smem + L_RS);

    // early prefetch: GEMM1 kc=0 B-frags + biases (independent of LDS)
    half8 bw[2];
    #pragma unroll
    for (int ni = 0; ni < 2; ni++)
        bw[ni] = *(const half8*)(w1p + (unsigned)(wv * 2 + ni) * 512 + lane * 8);
    float bv[2];
    #pragma unroll
    for (int ni = 0; ni < 2; ni++) bv[ni] = b1p[wv * 32 + ni * 16 + (lane & 15)];
    float c2 = b2[wv * 16 + (lane & 15)];

    // zero constant-pad slots: ccb slack row (8), ab slack (24), ab col39 (64)
    if (tid < 96) {
        if (tid < 8)       ccb[66 * 88 + tid] = (_Float16)0.f;
        else if (tid < 32) ab[64 * 40 + (tid - 8)] = (_Float16)0.f;
        else               ab[(tid - 32) * 40 + 39] = (_Float16)0.f;
    }

    // ---- 0d: joint angles -> ab (direct global; v/||v|| centering-invariant)
    #pragma unroll
    for (int r2 = 0; r2 < 2; r2++) {
        int i = r2 * TPB + tid;              // 0..1023
        int tt = i >> 4, e = i & 15;
        if (e < 13) {
            const float* P = poses + (size_t)(t0 + tt) * 75;
            int a0 = (int)((C0M >> (4 * e)) & 15) * 3;
            int a1 = (((int)((C1M >> (4 * e)) & 15)) + 1) * 3;
            float vx = P[a1] - P[a0], vy = P[a1+1] - P[a0+1], vz = P[a1+2] - P[a0+2];
            float d  = fmaf(vx, vx, fmaf(vy, vy, vz * vz));
            float inv = __builtin_amdgcn_rcpf(fmaxf(__builtin_amdgcn_sqrtf(d), 1e-12f));
            _Float16* A = ab + tt * 40;
            A[e * 3 + 0] = (_Float16)facos(fminf(fmaxf(vx * inv, -1.f), 1.f));
            A[e * 3 + 1] = (_Float16)facos(fminf(fmaxf(vy * inv, -1.f), 1.f));
            A[e * 3 + 2] = (_Float16)facos(fminf(fmaxf(vz * inv, -1.f), 1.f));
        }
    }

    // ---- 0ab: root + scale per frame (66 frames x 4 lanes, shfl reduce) ----
    // per-batch clamp: frames f=0,1 map to frame t0 when s0==0 (this makes
    // the temporal fold reproduce the reference's zero-padded vel/acc).
    if (tid < 264) {
        int f = tid >> 2, q = tid & 3;
        int g = t0 + f - 2;
        if (s0 == 0 && f < 2) g = t0;
        const float* P = poses + (size_t)g * 75;
        float r0 = P[0], r1 = P[1], r2 = P[2];
        float m2 = 0.f;
        #pragma unroll
        for (int jj = 0; jj < 7; jj++) {
            int j = q * 7 + jj;
            if (j < 25) {
                float dx = P[j*3]   - r0;
                float dy = P[j*3+1] - r1;
                float dz = P[j*3+2] - r2;
                m2 = fmaxf(m2, fmaf(dx, dx, fmaf(dy, dy, dz * dz)));
            }
        }
        m2 = fmaxf(m2, __shfl_xor(m2, 1));
        m2 = fmaxf(m2, __shfl_xor(m2, 2));
        if (q == 0) {
            float sc = __builtin_amdgcn_rcpf(__builtin_amdgcn_sqrtf(m2) + 1e-8f);
            rs[f] = make_float4(r0, r1, r2, sc);
        }
    }
    __syncthreads();

    // ---- 0c: center+scale -> ccb fp16 (j>=25 lanes zero cols 75..87) ----
    #pragma unroll 1
    for (int i = tid; i < 66 * 32; i += TPB) {
        int f = i >> 5, j = i & 31;
        _Float16* C = ccb + f * 88;
        if (j < 25) {
            int g = t0 + f - 2;
            if (s0 == 0 && f < 2) g = t0;
            const float* P = poses + (size_t)g * 75 + j * 3;
            float4 q = rs[f];
            C[j * 3 + 0] = (_Float16)((P[0] - q.x) * q.w);
            C[j * 3 + 1] = (_Float16)((P[1] - q.y) * q.w);
            C[j * 3 + 2] = (_Float16)((P[2] - q.z) * q.w);
        } else {
            int c = 75 + (j - 25) * 2;
            C[c] = (_Float16)0.f;
            if (c + 1 < 88) C[c + 1] = (_Float16)0.f;
        }
    }
    __syncthreads();

    // ---- GEMM1: hid = relu(A @ W1'' + b1'); K=352; bias in MFMA C-in ----
    floatx4 acc[4][2];
    #pragma unroll
    for (int mi = 0; mi < 4; mi++)
        #pragma unroll
        for (int ni = 0; ni < 2; ni++)
            acc[mi][ni] = (floatx4){bv[ni], bv[ni], bv[ni], bv[ni]};

    int rowb[4];
    #pragma unroll
    for (int mi = 0; mi < 4; mi++)           // (token+2)*88 + (l>>4)*8
        rowb[mi] = (mi * 16 + (lane & 15) + 2) * 88 + (lane >> 4) * 8;

    int koff = 0;                            // region walk (see r7)
    #pragma unroll 1
    for (int kc = 0; kc < 9; kc++) {         // cc regions d = kc/3
        half8 bn[2];
        #pragma unroll
        for (int ni = 0; ni < 2; ni++)
            bn[ni] = *(const half8*)(w1p + (unsigned)((kc + 1) * 16 + wv * 2 + ni) * 512 + lane * 8);
        half8 af[4];
        #pragma unroll
        for (int mi = 0; mi < 4; mi++)
            af[mi] = *(const half8*)(ccb + rowb[mi] + koff);
        #pragma unroll
        for (int mi = 0; mi < 4; mi++)
            #pragma unroll
            for (int ni = 0; ni < 2; ni++)
                acc[mi][ni] = __builtin_amdgcn_mfma_f32_16x16x32_f16(
                    af[mi], bw[ni], acc[mi][ni], 0, 0, 0);
        bw[0] = bn[0]; bw[1] = bn[1];
        koff += 32; if (kc == 2 || kc == 5) koff -= 184;   // next region
    }
    {   // kc = 9,10: angle region from ab
        int rowa[4];
        #pragma unroll
        for (int mi = 0; mi < 4; mi++)
            rowa[mi] = (mi * 16 + (lane & 15)) * 40 + (lane >> 4) * 8;
        #pragma unroll
        for (int kc = 9; kc < 11; kc++) {
            half8 bn[2];
            if (kc < 10) {
                #pragma unroll
                for (int ni = 0; ni < 2; ni++)
                    bn[ni] = *(const half8*)(w1p + (unsigned)((kc + 1) * 16 + wv * 2 + ni) * 512 + lane * 8);
            }
            half8 af[4];
            #pragma unroll
            for (int mi = 0; mi < 4; mi++)
                af[mi] = *(const half8*)(ab + rowa[mi] + (kc - 9) * 32);
            #pragma unroll
            for (int mi = 0; mi < 4; mi++)
                #pragma unroll
                for (int ni = 0; ni < 2; ni++)
                    acc[mi][ni] = __builtin_amdgcn_mfma_f32_16x16x32_f16(
                        af[mi], bw[ni], acc[mi][ni], 0, 0, 0);
            if (kc < 10) { bw[0] = bn[0]; bw[1] = bn[1]; }
        }
    }

    // preload W2 kc=0 frag (this wave's n-tile), independent of LDS
    half8 bw2 = *(const half8*)(w2p + (unsigned)wv * 512 + lane * 8);

    __syncthreads();   // all waves done reading ccb/ab/rs

    _Float16* hid = (_Float16*)smem;         // 64 x 264, overlays ccb/ab/rs
    #pragma unroll
    for (int mi = 0; mi < 4; mi++)
        #pragma unroll
        for (int ni = 0; ni < 2; ni++)
            #pragma unroll
            for (int r = 0; r < 4; r++) {
                float v = fmaxf(acc[mi][ni][r], 0.f);      // bias already in
                int m   = mi * 16 + (lane >> 4) * 4 + r;   // C/D: row=(l>>4)*4+r
                int col = wv * 32 + ni * 16 + (lane & 15); //      col=l&15
                hid[m * 264 + col] = (_Float16)v;
            }
    __syncthreads();   // hid visible

    // ---- GEMM2: out = hid @ W2 + b2; wave wv owns n-tile wv; b2 in C-in ----
    floatx4 acc2[4];
    #pragma unroll
    for (int mi = 0; mi < 4; mi++) acc2[mi] = (floatx4){c2, c2, c2, c2};

    #pragma unroll 1
    for (int kc = 0; kc < 8; kc++) {
        half8 bn2;
        if (kc < 7)
            bn2 = *(const half8*)(w2p + (unsigned)((kc + 1) * 8 + wv) * 512 + lane * 8);
        half8 af[4];
        #pragma unroll
        for (int mi = 0; mi < 4; mi++)
            af[mi] = *(const half8*)(hid + (mi * 16 + (lane & 15)) * 264 + kc * 32 + (lane >> 4) * 8);
        #pragma unroll
        for (int mi = 0; mi < 4; mi++)
            acc2[mi] = __builtin_amdgcn_mfma_f32_16x16x32_f16(
                af[mi], bw2, acc2[mi], 0, 0, 0);
        if (kc < 7) bw2 = bn2;
    }
    __syncthreads();   // all waves done reading hid (obuf overlays it)

    // ---- epilogue (r6-proven byte-exact): acc2 -> LDS fp32 (stride 132,
    //      2-way free), then contiguous per-lane float4 NONTEMPORAL stores
    //      (each wave = 1KB of fully-covered lines; WRITE_SIZE == 64MiB) ----
    float* obuf = (float*)smem;              // 64 x 132 f32
    #pragma unroll
    for (int mi = 0; mi < 4; mi++)
        #pragma unroll
        for (int r = 0; r < 4; r++) {
            int m = mi * 16 + (lane >> 4) * 4 + r;
            obuf[m * 132 + wv * 16 + (lane & 15)] = acc2[mi][r];
        }
    __syncthreads();
    #pragma unroll
    for (int k = 0; k < 4; k++) {
        int idx = k * TPB + tid;             // 0..2047 float4s
        int row = idx >> 5, c4 = idx & 31;
        f4_t v = *(const f4_t*)(obuf + row * 132 + c4 * 4);
        __builtin_nontemporal_store(v, (f4_t*)out + (size_t)t0 * 32 + idx);
    }
}

// --------------------------- launch -----------------------------------------
extern "C" void kernel_launch(void* const* d_in, const int* in_sizes, int n_in,
                              void* d_out, int out_size, void* d_ws, size_t ws_size,
                              hipStream_t stream) {
    (void)in_sizes; (void)n_in; (void)out_size; (void)ws_size;
    const float* poses = (const float*)d_in[0];
    const float* W1    = (const float*)d_in[1];
    const float* b1    = (const float*)d_in[2];
    const float* gamma = (const float*)d_in[3];
    const float* beta  = (const float*)d_in[4];
    const float* rmean = (const float*)d_in[5];
    const float* rvar  = (const float*)d_in[6];
    const float* W2    = (const float*)d_in[7];
    const float* b2    = (const float*)d_in[8];
    const float* jw    = (const float*)d_in[9];

    _Float16* w1p = (_Float16*)d_ws;                         // 352*256 fp16
    _Float16* w2p = w1p + 352 * HID_;                        // 256*128 fp16
    float* b1p = (float*)((char*)d_ws + (352 * HID_ + HID_ * OUT_) * 2);

    prep_kernel<<<481, 256, 0, stream>>>(W1, b1, gamma, beta, rmean, rvar, W2, jw,
                                         w1p, w2p, b1p);
    pose_mlp<<<2048, TPB, 0, stream>>>(poses, w1p, w2p, b1p, b2, (float*)d_out);
}